// Round 13
// baseline (579.198 us; speedup 1.0000x reference)
//
#include <hip/hip_runtime.h>
#include <math.h>

#define DDIM 16
#define NSTEPS 64
#define BATCH_N 2097152L   // fixed problem size: 2^21 rows (do NOT trust in_sizes units)
#define TABN 8192          // GELU table entries, u in [-16,16], h = 1/256
#define TILES 4            // row-tiles per wave: 4 = the only spill-free config (R8)
#define ROWS_PER_WAVE (16 * TILES)         // 64
#define ROWS_PER_BLOCK (4 * ROWS_PER_WAVE) // 256 (4 waves)

typedef _Float16 half4   __attribute__((ext_vector_type(4)));
typedef __fp16   fp16x2  __attribute__((ext_vector_type(2)));  // cvt_pkrtz return type
typedef float    floatx4 __attribute__((ext_vector_type(4)));

// Packed per-lane MFMA A-operand fragments for W^T and (V^T * 1/N), f16,
// plus the exact-erf GELU lookup table G(u) in f16 (g = G(u), scale 1/N in V).
__device__ half4    g_pw[NSTEPS * 64];
__device__ half4    g_pv[NSTEPS * 64];
__device__ _Float16 g_tab[TABN];

__global__ __launch_bounds__(256) void pack_wv(const float* __restrict__ W,
                                               const float* __restrict__ V)
{
    int t = blockIdx.x * 256 + threadIdx.x;   // 0..4095 = 64 steps * 64 lanes
    int L = t & 63;
    int s = t >> 6;
    int q = L >> 4, r = L & 15;
    const float vscale = 1.0f / (float)NSTEPS;
    const float* Ws = W + s * DDIM * DDIM;
    const float* Vs = V + s * DDIM * DDIM;
    half4 w, v;
    #pragma unroll
    for (int j = 0; j < 4; ++j) {
        w[j] = (_Float16)Ws[(4 * q + j) * DDIM + r];
        v[j] = (_Float16)(Vs[(4 * q + j) * DDIM + r] * vscale);
    }
    g_pw[t] = w;
    g_pv[t] = v;

    // GELU table: entry k <-> u_k = (k-4096)/256; value = exact-erf GELU(u_k),
    // f16 round-to-nearest storage.
    #pragma unroll
    for (int e = 0; e < 2; ++e) {
        int   k  = 2 * t + e;
        float u  = ((float)k - 4096.0f) * (1.0f / 256.0f);
        float gg = 0.5f * u * (1.0f + erff(u * 0.70710678f));
        g_tab[k] = (_Float16)gg;
    }
}

// ---------------------------------------------------------------------------
// R13: 50/50 LDS/trans split on the SPILL-FREE TILES=4 base.
// Ledger: conflicts track the LDS-path fraction perfectly (1.551/1.164/0.775e8
// at 4/4, 3/4, 2/4). R12's regression was NOT the split: FETCH/WRITE blew up
// 30-56% over ideal -> TILES=8 spills to scratch at VGPR=32 (h[8] alone = 32
// regs). All TILES=8 rounds spilled; only R8's TILES=4 matched ideal traffic.
// This round: TILES=4 (no spill), j=0,1 via LDS gather, j=2,3 via f32
// exp2-sigmoid on the trans pipe (both paths bit-validated in passing runs).
// Budget @~469cy/wave-step-slot: LDS ~52%, trans ~55%, VALU ~26% - balanced.
// ---------------------------------------------------------------------------
__global__ __launch_bounds__(256, 8) void resnet_mfma_kernel(
    const float* __restrict__ x,
    float* __restrict__ out)
{
    __shared__ _Float16 tab[TABN];   // 16 KB

    const int tid = threadIdx.x;

    // Block-copy table global -> LDS: 16384 B / (256 thr * 16 B) = 4 float4s.
    {
        const float4* src = reinterpret_cast<const float4*>(g_tab);
        float4*       dst = reinterpret_cast<float4*>(tab);
        #pragma unroll
        for (int k = 0; k < 4; ++k)
            dst[tid + 256 * k] = src[tid + 256 * k];
    }

    const int lane = tid & 63;
    const int wave = tid >> 6;
    const int q = lane >> 4, r = lane & 15;

    const long rowbase = (long)blockIdx.x * ROWS_PER_BLOCK
                       + (long)wave * ROWS_PER_WAVE;
    // Static bound check: max row = 8191*256 + 3*64 + 3*16 + 15 = 2097151. OK

    floatx4 h[TILES];
    #pragma unroll
    for (int t = 0; t < TILES; ++t) {
        const float4* p = reinterpret_cast<const float4*>(
            x + (rowbase + t * 16 + r) * DDIM + 4 * q);
        float4 v = *p;
        h[t][0] = v.x; h[t][1] = v.y; h[t][2] = v.z; h[t][3] = v.w;
    }

    // tanh-GELU sigmoid form for the trans-path elements:
    // g = u - u/(1+2^z), z = u * fma(Kc1, u^2, K)   (R3/R11-validated)
    const float K   = 2.3022082f;
    const float Kc1 = 0.10294340f;   // K * 0.044715

    half4 wf = g_pw[lane];
    half4 vf = g_pv[lane];

    const char* tabb = reinterpret_cast<const char*>(tab);

    __syncthreads();   // table ready

    for (int s = 0; s < NSTEPS; ++s) {
        int sn = (s < NSTEPS - 1) ? s + 1 : s;
        half4 wfn = g_pw[sn * 64 + lane];
        half4 vfn = g_pv[sn * 64 + lane];

        // Phase 1: h (fp32, C/D layout) -> f16 B-operand, all tiles.
        union { fp16x2 h2[2]; half4 h4; } hb[TILES];
        #pragma unroll
        for (int t = 0; t < TILES; ++t) {
            hb[t].h2[0] = __builtin_amdgcn_cvt_pkrtz(h[t][0], h[t][1]);
            hb[t].h2[1] = __builtin_amdgcn_cvt_pkrtz(h[t][2], h[t][3]);
        }

        // Phase 2: u = W^T @ h^T, all tiles (independent MFMAs).
        floatx4 u[TILES];
        #pragma unroll
        for (int t = 0; t < TILES; ++t) {
            floatx4 zero = {0.f, 0.f, 0.f, 0.f};
            u[t] = __builtin_amdgcn_mfma_f32_16x16x16f16(wf, hb[t].h4, zero, 0, 0, 0);
        }

        // Phase 3: GELU. j=0,1 via LDS table gather (3 VALU + ds_read_u16 each);
        // j=2,3 via trans-pipe sigmoid (5 VALU + 2 trans each), packed cvt.
        half4 gb[TILES];
        #pragma unroll
        for (int t = 0; t < TILES; ++t) {
            half4 g4;
            #pragma unroll
            for (int j = 0; j < 2; ++j) {
                int off = ((int)fmaf(u[t][j], 512.0f, 8193.0f)) & 16382;
                g4[j] = *reinterpret_cast<const _Float16*>(tabb + off);
            }
            float gt[2];
            #pragma unroll
            for (int j = 0; j < 2; ++j) {
                float xv = u[t][2 + j];
                float z  = xv * fmaf(Kc1, xv * xv, K);
                float e  = __builtin_amdgcn_exp2f(z);
                float rr = __builtin_amdgcn_rcpf(1.0f + e);
                gt[j] = fmaf(-xv, rr, xv);   // u*(1-sigmoid); limits clean
            }
            union { fp16x2 f2; _Float16 s[2]; } pk;
            pk.f2 = __builtin_amdgcn_cvt_pkrtz(gt[0], gt[1]);
            g4[2] = pk.s[0];
            g4[3] = pk.s[1];
            gb[t] = g4;
        }

        // Phase 4: h += g @ (V/N), all tiles (residual in MFMA C operand).
        #pragma unroll
        for (int t = 0; t < TILES; ++t) {
            h[t] = __builtin_amdgcn_mfma_f32_16x16x16f16(vf, gb[t], h[t], 0, 0, 0);
        }

        wf = wfn; vf = vfn;
    }

    #pragma unroll
    for (int t = 0; t < TILES; ++t) {
        float4 v = make_float4(h[t][0], h[t][1], h[t][2], h[t][3]);
        *reinterpret_cast<float4*>(out + (rowbase + t * 16 + r) * DDIM + 4 * q) = v;
    }
}

extern "C" void kernel_launch(void* const* d_in, const int* in_sizes, int n_in,
                              void* d_out, int out_size, void* d_ws, size_t ws_size,
                              hipStream_t stream) {
    (void)in_sizes; (void)n_in; (void)out_size; (void)d_ws; (void)ws_size;

    const float* x = (const float*)d_in[0];   // [2^21, 16] fp32
    const float* W = (const float*)d_in[1];   // [64, 16, 16] fp32
    const float* V = (const float*)d_in[2];   // [64, 16, 16] fp32
    float* out = (float*)d_out;

    pack_wv<<<16, 256, 0, stream>>>(W, V);

    // 256 rows per block (4 waves x 4 tiles x 16 rows); grid = 2^21/256 = 8192.
    resnet_mfma_kernel<<<(int)(BATCH_N / ROWS_PER_BLOCK), 256, 0, stream>>>(x, out);
}

// Round 14
// 536.790 us; speedup vs baseline: 1.0790x; 1.0790x over previous
//
#include <hip/hip_runtime.h>
#include <math.h>

#define DDIM 16
#define NSTEPS 64
#define BATCH_N 2097152L   // fixed problem size: 2^21 rows (do NOT trust in_sizes units)
#define TABN 8192          // GELU table entries, u in [-16,16], h = 1/256
#define TILES 4            // row-tiles per wave: 4 = spill-free (R8/R13 FETCH ideal)
#define ROWS_PER_WAVE (16 * TILES)         // 64
#define ROWS_PER_BLOCK (4 * ROWS_PER_WAVE) // 256 (4 waves)

typedef _Float16 half4   __attribute__((ext_vector_type(4)));
typedef __fp16   fp16x2  __attribute__((ext_vector_type(2)));  // cvt_pkrtz return type
typedef float    floatx4 __attribute__((ext_vector_type(4)));

// Packed per-lane MFMA A-operand fragments for W^T and (V^T * 1/N), f16,
// plus the exact-erf GELU lookup table G(u) in f16 (g = G(u), scale 1/N in V).
__device__ half4    g_pw[NSTEPS * 64];
__device__ half4    g_pv[NSTEPS * 64];
__device__ _Float16 g_tab[TABN];

__global__ __launch_bounds__(256) void pack_wv(const float* __restrict__ W,
                                               const float* __restrict__ V)
{
    int t = blockIdx.x * 256 + threadIdx.x;   // 0..4095 = 64 steps * 64 lanes
    int L = t & 63;
    int s = t >> 6;
    int q = L >> 4, r = L & 15;
    const float vscale = 1.0f / (float)NSTEPS;
    const float* Ws = W + s * DDIM * DDIM;
    const float* Vs = V + s * DDIM * DDIM;
    half4 w, v;
    #pragma unroll
    for (int j = 0; j < 4; ++j) {
        w[j] = (_Float16)Ws[(4 * q + j) * DDIM + r];
        v[j] = (_Float16)(Vs[(4 * q + j) * DDIM + r] * vscale);
    }
    g_pw[t] = w;
    g_pv[t] = v;

    // GELU table: entry k <-> u_k = (k-4096)/256; value = exact-erf GELU(u_k),
    // f16 round-to-nearest storage.
    #pragma unroll
    for (int e = 0; e < 2; ++e) {
        int   k  = 2 * t + e;
        float u  = ((float)k - 4096.0f) * (1.0f / 256.0f);
        float gg = 0.5f * u * (1.0f + erff(u * 0.70710678f));
        g_tab[k] = (_Float16)gg;
    }
}

// ---------------------------------------------------------------------------
// R14: 3/4 LDS + 1/4 trans on the spill-free TILES=4 base (R11's split, clean).
// Marginal-cost ledger (dur/conflicts/FETCH only; derived from R8/R11/R13):
//   - LDS elem marginal: ~280k cy/CU while LDS saturated, ~100k after;
//   - trans elem marginal: ~230k cy (trans blocks its wave ~16cy/op; TLP
//     doesn't fully cover) -> optimum = smallest trans share that just
//     de-saturates LDS = 3/4 LDS + 1/4 trans.
// R11 ran this split but spilled (TILES=8: FETCH +12MB, WRITE +24MB); R13
// proved TILES=4 runs at exactly-ideal traffic. Single change vs R13: the
// element split (j=0,1,2 LDS gather; j=3 trans sigmoid).
// Model: LDS 848k cy/CU (binding), trans 262k/SIMD, VALU ~295k/SIMD.
// ---------------------------------------------------------------------------
__global__ __launch_bounds__(256, 8) void resnet_mfma_kernel(
    const float* __restrict__ x,
    float* __restrict__ out)
{
    __shared__ _Float16 tab[TABN];   // 16 KB

    const int tid = threadIdx.x;

    // Block-copy table global -> LDS: 16384 B / (256 thr * 16 B) = 4 float4s.
    {
        const float4* src = reinterpret_cast<const float4*>(g_tab);
        float4*       dst = reinterpret_cast<float4*>(tab);
        #pragma unroll
        for (int k = 0; k < 4; ++k)
            dst[tid + 256 * k] = src[tid + 256 * k];
    }

    const int lane = tid & 63;
    const int wave = tid >> 6;
    const int q = lane >> 4, r = lane & 15;

    const long rowbase = (long)blockIdx.x * ROWS_PER_BLOCK
                       + (long)wave * ROWS_PER_WAVE;
    // Static bound check: max row = 8191*256 + 3*64 + 3*16 + 15 = 2097151. OK

    floatx4 h[TILES];
    #pragma unroll
    for (int t = 0; t < TILES; ++t) {
        const float4* p = reinterpret_cast<const float4*>(
            x + (rowbase + t * 16 + r) * DDIM + 4 * q);
        float4 v = *p;
        h[t][0] = v.x; h[t][1] = v.y; h[t][2] = v.z; h[t][3] = v.w;
    }

    // tanh-GELU sigmoid form for the trans-path element:
    // g = u - u/(1+2^z), z = u * fma(Kc1, u^2, K)   (R3/R11-validated)
    const float K   = 2.3022082f;
    const float Kc1 = 0.10294340f;   // K * 0.044715

    half4 wf = g_pw[lane];
    half4 vf = g_pv[lane];

    const char* tabb = reinterpret_cast<const char*>(tab);

    __syncthreads();   // table ready

    for (int s = 0; s < NSTEPS; ++s) {
        int sn = (s < NSTEPS - 1) ? s + 1 : s;
        half4 wfn = g_pw[sn * 64 + lane];
        half4 vfn = g_pv[sn * 64 + lane];

        // Phase 1: h (fp32, C/D layout) -> f16 B-operand, all tiles.
        union { fp16x2 h2[2]; half4 h4; } hb[TILES];
        #pragma unroll
        for (int t = 0; t < TILES; ++t) {
            hb[t].h2[0] = __builtin_amdgcn_cvt_pkrtz(h[t][0], h[t][1]);
            hb[t].h2[1] = __builtin_amdgcn_cvt_pkrtz(h[t][2], h[t][3]);
        }

        // Phase 2: u = W^T @ h^T, all tiles (independent MFMAs).
        floatx4 u[TILES];
        #pragma unroll
        for (int t = 0; t < TILES; ++t) {
            floatx4 zero = {0.f, 0.f, 0.f, 0.f};
            u[t] = __builtin_amdgcn_mfma_f32_16x16x16f16(wf, hb[t].h4, zero, 0, 0, 0);
        }

        // Phase 3: GELU. j=0,1,2 via LDS table gather (3 VALU + ds_read_u16);
        // j=3 via trans-pipe sigmoid (5 VALU + exp2 + rcp, per-elem indep).
        half4 gb[TILES];
        #pragma unroll
        for (int t = 0; t < TILES; ++t) {
            half4 g4;
            #pragma unroll
            for (int j = 0; j < 3; ++j) {
                int off = ((int)fmaf(u[t][j], 512.0f, 8193.0f)) & 16382;
                g4[j] = *reinterpret_cast<const _Float16*>(tabb + off);
            }
            {
                float xv = u[t][3];
                float z  = xv * fmaf(Kc1, xv * xv, K);
                float e  = __builtin_amdgcn_exp2f(z);
                float rr = __builtin_amdgcn_rcpf(1.0f + e);
                g4[3] = (_Float16)fmaf(-xv, rr, xv);   // u*(1-sigmoid); limits clean
            }
            gb[t] = g4;
        }

        // Phase 4: h += g @ (V/N), all tiles (residual in MFMA C operand).
        #pragma unroll
        for (int t = 0; t < TILES; ++t) {
            h[t] = __builtin_amdgcn_mfma_f32_16x16x16f16(vf, gb[t], h[t], 0, 0, 0);
        }

        wf = wfn; vf = vfn;
    }

    #pragma unroll
    for (int t = 0; t < TILES; ++t) {
        float4 v = make_float4(h[t][0], h[t][1], h[t][2], h[t][3]);
        *reinterpret_cast<float4*>(out + (rowbase + t * 16 + r) * DDIM + 4 * q) = v;
    }
}

extern "C" void kernel_launch(void* const* d_in, const int* in_sizes, int n_in,
                              void* d_out, int out_size, void* d_ws, size_t ws_size,
                              hipStream_t stream) {
    (void)in_sizes; (void)n_in; (void)out_size; (void)d_ws; (void)ws_size;

    const float* x = (const float*)d_in[0];   // [2^21, 16] fp32
    const float* W = (const float*)d_in[1];   // [64, 16, 16] fp32
    const float* V = (const float*)d_in[2];   // [64, 16, 16] fp32
    float* out = (float*)d_out;

    pack_wv<<<16, 256, 0, stream>>>(W, V);

    // 256 rows per block (4 waves x 4 tiles x 16 rows); grid = 2^21/256 = 8192.
    resnet_mfma_kernel<<<(int)(BATCH_N / ROWS_PER_BLOCK), 256, 0, stream>>>(x, out);
}

// Round 15
// 527.024 us; speedup vs baseline: 1.0990x; 1.0185x over previous
//
#include <hip/hip_runtime.h>
#include <math.h>

#define DDIM 16
#define NSTEPS 64
#define BATCH_N 2097152L   // fixed problem size: 2^21 rows (do NOT trust in_sizes units)
#define TABN 8192          // GELU table entries, u in [-16,16], h = 1/256
#define TILES 4            // row-tiles per wave: 4 = spill-free (R8/R13/R14 FETCH ideal)
#define ROWS_PER_WAVE (16 * TILES)         // 64
#define ROWS_PER_BLOCK (4 * ROWS_PER_WAVE) // 256 (4 waves)

typedef _Float16 half4   __attribute__((ext_vector_type(4)));
typedef __fp16   fp16x2  __attribute__((ext_vector_type(2)));  // cvt_pkrtz return type
typedef float    floatx4 __attribute__((ext_vector_type(4)));

// Packed per-lane MFMA A-operand fragments for W^T and (V^T * 1/N), f16,
// plus the exact-erf GELU lookup table G(u) in f16 (g = G(u), scale 1/N in V).
__device__ half4    g_pw[NSTEPS * 64];
__device__ half4    g_pv[NSTEPS * 64];
__device__ _Float16 g_tab[TABN];

__global__ __launch_bounds__(256) void pack_wv(const float* __restrict__ W,
                                               const float* __restrict__ V)
{
    int t = blockIdx.x * 256 + threadIdx.x;   // 0..4095 = 64 steps * 64 lanes
    int L = t & 63;
    int s = t >> 6;
    int q = L >> 4, r = L & 15;
    const float vscale = 1.0f / (float)NSTEPS;
    const float* Ws = W + s * DDIM * DDIM;
    const float* Vs = V + s * DDIM * DDIM;
    half4 w, v;
    #pragma unroll
    for (int j = 0; j < 4; ++j) {
        w[j] = (_Float16)Ws[(4 * q + j) * DDIM + r];
        v[j] = (_Float16)(Vs[(4 * q + j) * DDIM + r] * vscale);
    }
    g_pw[t] = w;
    g_pv[t] = v;

    // GELU table: entry k <-> u_k = (k-4096)/256; value = exact-erf GELU(u_k),
    // f16 round-to-nearest storage.
    #pragma unroll
    for (int e = 0; e < 2; ++e) {
        int   k  = 2 * t + e;
        float u  = ((float)k - 4096.0f) * (1.0f / 256.0f);
        float gg = 0.5f * u * (1.0f + erff(u * 0.70710678f));
        g_tab[k] = (_Float16)gg;
    }
}

// ---------------------------------------------------------------------------
// R15 = R14 + cross-tile batched reciprocal on the trans path.
// Ledger: split curve complete (4/4=455, 3/4=434 opt, 2/4=489); conflicts obey
// the split law exactly; traffic ideal. Residual budget: LDS ~62% (random-
// gather conflicts, irreducible), VALU ~27%, trans ~25%, MFMA ~28% -> only
// outright op removal helps. This round: the 4 trans elements' rcp(1+e_t)
// batched via one rcp of the product + 9 recovery muls (R4's trick, applied
// where it pays): trans 8 -> 5 ops/step (-48cy), VALU +18cy.
// Safety: d_t >= 1; z <= 2.3*8 -> prod <= 2^74 (no overflow); hypothetical
// overflow gives rr=0 -> g=u = correct positive-side limit. Recovery muls add
// ~2ulp on rr, invisible under f16 g-quantization.
// ---------------------------------------------------------------------------
__global__ __launch_bounds__(256, 8) void resnet_mfma_kernel(
    const float* __restrict__ x,
    float* __restrict__ out)
{
    __shared__ _Float16 tab[TABN];   // 16 KB

    const int tid = threadIdx.x;

    // Block-copy table global -> LDS: 16384 B / (256 thr * 16 B) = 4 float4s.
    {
        const float4* src = reinterpret_cast<const float4*>(g_tab);
        float4*       dst = reinterpret_cast<float4*>(tab);
        #pragma unroll
        for (int k = 0; k < 4; ++k)
            dst[tid + 256 * k] = src[tid + 256 * k];
    }

    const int lane = tid & 63;
    const int wave = tid >> 6;
    const int q = lane >> 4, r = lane & 15;

    const long rowbase = (long)blockIdx.x * ROWS_PER_BLOCK
                       + (long)wave * ROWS_PER_WAVE;
    // Static bound check: max row = 8191*256 + 3*64 + 3*16 + 15 = 2097151. OK

    floatx4 h[TILES];
    #pragma unroll
    for (int t = 0; t < TILES; ++t) {
        const float4* p = reinterpret_cast<const float4*>(
            x + (rowbase + t * 16 + r) * DDIM + 4 * q);
        float4 v = *p;
        h[t][0] = v.x; h[t][1] = v.y; h[t][2] = v.z; h[t][3] = v.w;
    }

    // tanh-GELU sigmoid form for the trans-path element:
    // g = u - u*rr, rr = 1/(1+2^z), z = u * fma(Kc1, u^2, K)  (R3/R14-validated)
    const float K   = 2.3022082f;
    const float Kc1 = 0.10294340f;   // K * 0.044715

    half4 wf = g_pw[lane];
    half4 vf = g_pv[lane];

    const char* tabb = reinterpret_cast<const char*>(tab);

    __syncthreads();   // table ready

    for (int s = 0; s < NSTEPS; ++s) {
        int sn = (s < NSTEPS - 1) ? s + 1 : s;
        half4 wfn = g_pw[sn * 64 + lane];
        half4 vfn = g_pv[sn * 64 + lane];

        // Phase 1: h (fp32, C/D layout) -> f16 B-operand, all tiles.
        union { fp16x2 h2[2]; half4 h4; } hb[TILES];
        #pragma unroll
        for (int t = 0; t < TILES; ++t) {
            hb[t].h2[0] = __builtin_amdgcn_cvt_pkrtz(h[t][0], h[t][1]);
            hb[t].h2[1] = __builtin_amdgcn_cvt_pkrtz(h[t][2], h[t][3]);
        }

        // Phase 2: u = W^T @ h^T, all tiles (independent MFMAs).
        floatx4 u[TILES];
        #pragma unroll
        for (int t = 0; t < TILES; ++t) {
            floatx4 zero = {0.f, 0.f, 0.f, 0.f};
            u[t] = __builtin_amdgcn_mfma_f32_16x16x16f16(wf, hb[t].h4, zero, 0, 0, 0);
        }

        // Phase 3a: j=0,1,2 via LDS table gather (3 VALU + ds_read_u16 each).
        half4 gb[TILES];
        #pragma unroll
        for (int t = 0; t < TILES; ++t) {
            #pragma unroll
            for (int j = 0; j < 3; ++j) {
                int off = ((int)fmaf(u[t][j], 512.0f, 8193.0f)) & 16382;
                gb[t][j] = *reinterpret_cast<const _Float16*>(tabb + off);
            }
        }

        // Phase 3b: j=3 of all 4 tiles via trans pipe, rcp 4-batched:
        // 4 exp2 + 1 rcp (was 4+4) + 9 recovery muls.
        {
            float d[TILES];
            #pragma unroll
            for (int t = 0; t < TILES; ++t) {
                float xv = u[t][3];
                float z  = xv * fmaf(Kc1, xv * xv, K);
                d[t] = 1.0f + __builtin_amdgcn_exp2f(z);
            }
            float p01 = d[0] * d[1];
            float p23 = d[2] * d[3];
            float R   = __builtin_amdgcn_rcpf(p01 * p23);
            float r01 = R * p23, r23 = R * p01;
            float rr[TILES] = { r01 * d[1], r01 * d[0], r23 * d[3], r23 * d[2] };
            #pragma unroll
            for (int t = 0; t < TILES; ++t)
                gb[t][3] = (_Float16)fmaf(-u[t][3], rr[t], u[t][3]);
        }

        // Phase 4: h += g @ (V/N), all tiles (residual in MFMA C operand).
        #pragma unroll
        for (int t = 0; t < TILES; ++t) {
            h[t] = __builtin_amdgcn_mfma_f32_16x16x16f16(vf, gb[t], h[t], 0, 0, 0);
        }

        wf = wfn; vf = vfn;
    }

    #pragma unroll
    for (int t = 0; t < TILES; ++t) {
        float4 v = make_float4(h[t][0], h[t][1], h[t][2], h[t][3]);
        *reinterpret_cast<float4*>(out + (rowbase + t * 16 + r) * DDIM + 4 * q) = v;
    }
}

extern "C" void kernel_launch(void* const* d_in, const int* in_sizes, int n_in,
                              void* d_out, int out_size, void* d_ws, size_t ws_size,
                              hipStream_t stream) {
    (void)in_sizes; (void)n_in; (void)out_size; (void)d_ws; (void)ws_size;

    const float* x = (const float*)d_in[0];   // [2^21, 16] fp32
    const float* W = (const float*)d_in[1];   // [64, 16, 16] fp32
    const float* V = (const float*)d_in[2];   // [64, 16, 16] fp32
    float* out = (float*)d_out;

    pack_wv<<<16, 256, 0, stream>>>(W, V);

    // 256 rows per block (4 waves x 4 tiles x 16 rows); grid = 2^21/256 = 8192.
    resnet_mfma_kernel<<<(int)(BATCH_N / ROWS_PER_BLOCK), 256, 0, stream>>>(x, out);
}